// Round 1
// baseline (1087.755 us; speedup 1.0000x reference)
//
#include <hip/hip_runtime.h>
#include <math.h>

namespace {
constexpr int DIMC  = 1024;
constexpr int NH    = 16;
constexpr int HD    = 64;
constexpr int SEQ   = 2048;
constexpr int BATCH = 2;
constexpr float SCL = 0.125f;  // 1/(tau*sqrt(64))
}

// C = A @ W^T + bias.  A:[M,K] rm, W:[N,K] rm.
// OUT_HEADS==1: write to [B,H,S,hd] head-interleaved layout; else [M,N].
template<int OUT_HEADS>
__global__ __launch_bounds__(256)
void gemm_nt_bias(const float* __restrict__ A, const float* __restrict__ W,
                  const float* __restrict__ bias, float* __restrict__ C,
                  int M, int N, int K) {
  __shared__ float As[16][68];  // [k][m] transposed
  __shared__ float Ws[16][68];  // [k][n] transposed
  const int tid = threadIdx.x;
  const int tx = tid & 15, ty = tid >> 4;
  const int bm = blockIdx.x * 64, bn = blockIdx.y * 64;
  const int lr = tid >> 2;          // 0..63 row within tile
  const int lk = (tid & 3) * 4;     // 0,4,8,12

  float acc[4][4] = {};

  for (int k0 = 0; k0 < K; k0 += 16) {
    const float4 av = *(const float4*)&A[(size_t)(bm + lr) * K + k0 + lk];
    const float4 wv = *(const float4*)&W[(size_t)(bn + lr) * K + k0 + lk];
    __syncthreads();   // previous compute done before overwrite
    As[lk+0][lr] = av.x; As[lk+1][lr] = av.y; As[lk+2][lr] = av.z; As[lk+3][lr] = av.w;
    Ws[lk+0][lr] = wv.x; Ws[lk+1][lr] = wv.y; Ws[lk+2][lr] = wv.z; Ws[lk+3][lr] = wv.w;
    __syncthreads();
#pragma unroll
    for (int kk = 0; kk < 16; ++kk) {
      const float4 a = *(const float4*)&As[kk][ty * 4];
      const float4 b = *(const float4*)&Ws[kk][tx * 4];
      const float ar[4] = {a.x, a.y, a.z, a.w};
      const float br[4] = {b.x, b.y, b.z, b.w};
#pragma unroll
      for (int i = 0; i < 4; ++i)
#pragma unroll
        for (int j = 0; j < 4; ++j)
          acc[i][j] = fmaf(ar[i], br[j], acc[i][j]);
    }
  }

#pragma unroll
  for (int i = 0; i < 4; ++i) {
    const int m = bm + ty * 4 + i;
    const int n0 = bn + tx * 4;
    float4 ov;
    const float4 bv = *(const float4*)&bias[n0];
    ov.x = acc[i][0] + bv.x; ov.y = acc[i][1] + bv.y;
    ov.z = acc[i][2] + bv.z; ov.w = acc[i][3] + bv.w;
    if (OUT_HEADS) {
      const int b = m >> 11, s = m & (SEQ - 1);
      const int h = n0 >> 6, d = n0 & (HD - 1);
      *(float4*)&C[(((size_t)(b * NH + h) * SEQ + s) * HD) + d] = ov;
    } else {
      *(float4*)&C[(size_t)m * N + n0] = ov;
    }
  }
}

// Flash attention fp32 + fused local-diffusion blend.
// Q,K,V: [B*H, S, hd].  Y: [B, S, D] (head de-interleaved on write).
__global__ __launch_bounds__(256)
void attn_fp32(const float* __restrict__ Q, const float* __restrict__ K,
               const float* __restrict__ V, float* __restrict__ Y) {
  __shared__ float Qs[HD][68];  // [d][r]
  __shared__ float Ks[HD][68];  // [d][c]
  __shared__ float Vs[64][68];  // [k][d]
  __shared__ float Ps[64][68];  // [k][r]

  const int tid = threadIdx.x;
  const int tx = tid & 15, ty = tid >> 4;
  const int bh = blockIdx.y;
  const int q0 = blockIdx.x * 64;
  const float* Qp = Q + (size_t)bh * SEQ * HD;
  const float* Kp = K + (size_t)bh * SEQ * HD;
  const float* Vp = V + (size_t)bh * SEQ * HD;

  // stage Q tile transposed
  {
    const int d4 = (tid & 15) * 4;
#pragma unroll
    for (int rr = 0; rr < 4; ++rr) {
      const int r = (tid >> 4) * 4 + rr;
      const float4 qv = *(const float4*)&Qp[(size_t)(q0 + r) * HD + d4];
      Qs[d4 + 0][r] = qv.x; Qs[d4 + 1][r] = qv.y;
      Qs[d4 + 2][r] = qv.z; Qs[d4 + 3][r] = qv.w;
    }
  }

  float O[4][4] = {};
  float mrow[4] = {-INFINITY, -INFINITY, -INFINITY, -INFINITY};
  float lrow[4] = {0.f, 0.f, 0.f, 0.f};

  for (int kt = 0; kt < SEQ / 64; ++kt) {
    const int kb = kt * 64;
    __syncthreads();   // previous PV done with Ks/Vs/Ps
    {
      const int d4 = (tid & 15) * 4;
#pragma unroll
      for (int rr = 0; rr < 4; ++rr) {
        const int r = (tid >> 4) * 4 + rr;
        const float4 kv = *(const float4*)&Kp[(size_t)(kb + r) * HD + d4];
        const float4 vv = *(const float4*)&Vp[(size_t)(kb + r) * HD + d4];
        Ks[d4 + 0][r] = kv.x; Ks[d4 + 1][r] = kv.y;
        Ks[d4 + 2][r] = kv.z; Ks[d4 + 3][r] = kv.w;
        *(float4*)&Vs[r][d4] = vv;
      }
    }
    __syncthreads();

    // scores: sc[i][j] = sum_d Q[4ty+i][d] * K[4tx+j][d]
    float sc[4][4] = {};
#pragma unroll 8
    for (int d = 0; d < HD; ++d) {
      const float4 a = *(const float4*)&Qs[d][ty * 4];
      const float4 b = *(const float4*)&Ks[d][tx * 4];
      const float ar[4] = {a.x, a.y, a.z, a.w};
      const float br[4] = {b.x, b.y, b.z, b.w};
#pragma unroll
      for (int i = 0; i < 4; ++i)
#pragma unroll
        for (int j = 0; j < 4; ++j)
          sc[i][j] = fmaf(ar[i], br[j], sc[i][j]);
    }

    // online softmax update
    float p[4][4];
#pragma unroll
    for (int i = 0; i < 4; ++i) {
      float tm = fmaxf(fmaxf(sc[i][0], sc[i][1]), fmaxf(sc[i][2], sc[i][3]));
#pragma unroll
      for (int o = 1; o < 16; o <<= 1) tm = fmaxf(tm, __shfl_xor(tm, o));
      tm *= SCL;
      const float newm = fmaxf(mrow[i], tm);
      const float resc = __expf(mrow[i] - newm);
      float rs = 0.f;
#pragma unroll
      for (int j = 0; j < 4; ++j) {
        p[i][j] = __expf(sc[i][j] * SCL - newm);
        rs += p[i][j];
      }
#pragma unroll
      for (int o = 1; o < 16; o <<= 1) rs += __shfl_xor(rs, o);
      lrow[i] = lrow[i] * resc + rs;
      mrow[i] = newm;
#pragma unroll
      for (int j = 0; j < 4; ++j) O[i][j] *= resc;
    }

    // store P transposed: Ps[key][row]
#pragma unroll
    for (int i = 0; i < 4; ++i)
#pragma unroll
      for (int j = 0; j < 4; ++j)
        Ps[tx * 4 + j][ty * 4 + i] = p[i][j];
    __syncthreads();

    // PV: O[i][j] += sum_k P[4ty+i][k] * V[k][4tx+j]
#pragma unroll 8
    for (int k = 0; k < 64; ++k) {
      const float4 pa = *(const float4*)&Ps[k][ty * 4];
      const float4 vb = *(const float4*)&Vs[k][tx * 4];
      const float pr[4] = {pa.x, pa.y, pa.z, pa.w};
      const float vr[4] = {vb.x, vb.y, vb.z, vb.w};
#pragma unroll
      for (int i = 0; i < 4; ++i)
#pragma unroll
        for (int j = 0; j < 4; ++j)
          O[i][j] = fmaf(pr[i], vr[j], O[i][j]);
    }
  }

  // epilogue: 0.6*softmax@V + 0.4*(L@V), write to [B,S,D]
  const int b = bh >> 4, h = bh & 15;
  const float e1 = __expf(-3.125f);   // exp(-1/0.32)
  const float e2 = __expf(-12.5f);
  const float e3 = __expf(-28.125f);
  const float lw[7] = {e3, e2, e1, 1.f, e1, e2, e3};
#pragma unroll
  for (int i = 0; i < 4; ++i) {
    const int q = q0 + ty * 4 + i;
    const float inv_l = 0.6f / lrow[i];
    float wsum = 0.f;
#pragma unroll
    for (int dd = -3; dd <= 3; ++dd) {
      const int k = q + dd;
      if (k >= 0 && k < SEQ) wsum += lw[dd + 3];
    }
    const float wnorm = 0.4f / (wsum + 1e-10f);
    float loc[4] = {0.f, 0.f, 0.f, 0.f};
#pragma unroll
    for (int dd = -3; dd <= 3; ++dd) {
      const int k = q + dd;
      if (k >= 0 && k < SEQ) {
        const float4 vv = *(const float4*)&Vp[(size_t)k * HD + tx * 4];
        const float w = lw[dd + 3];
        loc[0] = fmaf(w, vv.x, loc[0]);
        loc[1] = fmaf(w, vv.y, loc[1]);
        loc[2] = fmaf(w, vv.z, loc[2]);
        loc[3] = fmaf(w, vv.w, loc[3]);
      }
    }
    float4 ov;
    ov.x = O[i][0] * inv_l + loc[0] * wnorm;
    ov.y = O[i][1] * inv_l + loc[1] * wnorm;
    ov.z = O[i][2] * inv_l + loc[2] * wnorm;
    ov.w = O[i][3] * inv_l + loc[3] * wnorm;
    *(float4*)&Y[(size_t)(b * SEQ + q) * DIMC + h * HD + tx * 4] = ov;
  }
}

extern "C" void kernel_launch(void* const* d_in, const int* in_sizes, int n_in,
                              void* d_out, int out_size, void* d_ws, size_t ws_size,
                              hipStream_t stream) {
  (void)in_sizes; (void)n_in; (void)out_size; (void)ws_size;
  const float* x  = (const float*)d_in[0];
  const float* Wq = (const float*)d_in[1];
  const float* bq = (const float*)d_in[2];
  const float* Wk = (const float*)d_in[3];
  const float* bk = (const float*)d_in[4];
  const float* Wv = (const float*)d_in[5];
  const float* bv = (const float*)d_in[6];
  const float* Wo = (const float*)d_in[7];
  const float* bo = (const float*)d_in[8];
  float* out = (float*)d_out;

  char* ws = (char*)d_ws;
  const size_t SZ = (size_t)BATCH * NH * SEQ * HD * sizeof(float);  // 16.78 MB
  float* Qh = (float*)(ws);
  float* Kh = (float*)(ws + SZ);
  float* Vh = (float*)(ws + 2 * SZ);
  float* Yb = (float*)(ws + 3 * SZ);

  const int M = BATCH * SEQ;
  dim3 blk(256);
  dim3 g1(M / 64, DIMC / 64);
  gemm_nt_bias<1><<<g1, blk, 0, stream>>>(x, Wq, bq, Qh, M, DIMC, DIMC);
  gemm_nt_bias<1><<<g1, blk, 0, stream>>>(x, Wk, bk, Kh, M, DIMC, DIMC);
  gemm_nt_bias<1><<<g1, blk, 0, stream>>>(x, Wv, bv, Vh, M, DIMC, DIMC);

  dim3 g2(SEQ / 64, BATCH * NH);
  attn_fp32<<<g2, blk, 0, stream>>>(Qh, Kh, Vh, Yb);

  gemm_nt_bias<0><<<g1, blk, 0, stream>>>(Yb, Wo, bo, out, M, DIMC, DIMC);
}

// Round 2
// 255.345 us; speedup vs baseline: 4.2599x; 4.2599x over previous
//
#include <hip/hip_runtime.h>
#include <math.h>

typedef __bf16 bf16x8 __attribute__((ext_vector_type(8)));
typedef float f32x4 __attribute__((ext_vector_type(4)));

namespace {
constexpr int DIMC = 1024, NH = 16, HD = 64, SEQ = 2048, BATCH = 2;
constexpr float SCL = 0.125f;  // 1/(tau*sqrt(64))
}

__device__ __forceinline__ unsigned short f2b(float f) {
  unsigned u = __float_as_uint(f);
  return (unsigned short)((u + 0x7fffu + ((u >> 16) & 1u)) >> 16);
}
__device__ __forceinline__ float b2f(unsigned short s) {
  return __uint_as_float((unsigned)s << 16);
}

// fp32 -> bf16 (RNE), 8 elements per thread
__global__ __launch_bounds__(256)
void cvt_bf16(const float* __restrict__ in, unsigned short* __restrict__ out, int n8) {
  int i = blockIdx.x * 256 + threadIdx.x;
  if (i >= n8) return;
  const float4* in4 = (const float4*)in;
  float4 a = in4[2 * i], b = in4[2 * i + 1];
  union { unsigned short u[8]; uint4 v; } r;
  r.u[0] = f2b(a.x); r.u[1] = f2b(a.y); r.u[2] = f2b(a.z); r.u[3] = f2b(a.w);
  r.u[4] = f2b(b.x); r.u[5] = f2b(b.y); r.u[6] = f2b(b.z); r.u[7] = f2b(b.w);
  ((uint4*)out)[i] = r.v;
}

// C = A @ W^T + bias.  A:[4096,1024] bf16 rm, W:[1024,1024] bf16 rm.
// MODE 0: fp32 [M,N] out.  MODE 1: bf16 head-interleaved [B*H,S,hd] out.
// BM=128, BN=64, BK=32; 4 waves (2x2), each 64x32 = 4x2 mfma frags.
template<int MODE>
__global__ __launch_bounds__(256, 2)
void gemm_bf16(const unsigned short* __restrict__ A, const unsigned short* __restrict__ W,
               const float* __restrict__ bias, void* __restrict__ Cout) {
  __shared__ char As[8192];  // [128][32] bf16, 64 B rows
  __shared__ char Bs[4096];  // [64][32] bf16
  const int tid = threadIdx.x, lane = tid & 63, w = tid >> 6;
  const int p = lane & 15, g = lane >> 4;
  const int wr = w >> 1, wc = w & 1;
  const int bm = blockIdx.x * 128, bn = blockIdx.y * 64;
  const int sr = tid >> 2, sc = (tid & 3) * 8;

  f32x4 acc[4][2];
#pragma unroll
  for (int mf = 0; mf < 4; ++mf)
#pragma unroll
    for (int nf = 0; nf < 2; ++nf)
      acc[mf][nf] = (f32x4){0.f, 0.f, 0.f, 0.f};

  const size_t arow0 = (size_t)(bm + sr) * DIMC + sc;
  const size_t arow1 = (size_t)(bm + 64 + sr) * DIMC + sc;
  const size_t brow  = (size_t)(bn + sr) * DIMC + sc;

  for (int k0 = 0; k0 < DIMC; k0 += 32) {
    const bf16x8 va0 = *(const bf16x8*)&A[arow0 + k0];
    const bf16x8 va1 = *(const bf16x8*)&A[arow1 + k0];
    const bf16x8 vb  = *(const bf16x8*)&W[brow + k0];
    __syncthreads();   // previous tile's reads complete
    *(bf16x8*)&As[tid * 16] = va0;
    *(bf16x8*)&As[4096 + tid * 16] = va1;
    *(bf16x8*)&Bs[tid * 16] = vb;
    __syncthreads();
    bf16x8 af[4], bfr[2];
#pragma unroll
    for (int mf = 0; mf < 4; ++mf)
      af[mf] = *(const bf16x8*)&As[(wr * 64 + mf * 16 + p) * 64 + g * 16];
#pragma unroll
    for (int nf = 0; nf < 2; ++nf)
      bfr[nf] = *(const bf16x8*)&Bs[(wc * 32 + nf * 16 + p) * 64 + g * 16];
#pragma unroll
    for (int mf = 0; mf < 4; ++mf)
#pragma unroll
      for (int nf = 0; nf < 2; ++nf)
        acc[mf][nf] = __builtin_amdgcn_mfma_f32_16x16x32_bf16(af[mf], bfr[nf], acc[mf][nf], 0, 0, 0);
  }

  // epilogue: C/D layout col=lane&15, row=(lane>>4)*4+j  [m89/m91 verified]
#pragma unroll
  for (int nf = 0; nf < 2; ++nf) {
    const int cg = bn + wc * 32 + nf * 16 + p;
    const float bv = bias[cg];
#pragma unroll
    for (int mf = 0; mf < 4; ++mf) {
#pragma unroll
      for (int j = 0; j < 4; ++j) {
        const int rg = bm + wr * 64 + mf * 16 + g * 4 + j;
        const float v = acc[mf][nf][j] + bv;
        if (MODE == 0) {
          ((float*)Cout)[(size_t)rg * DIMC + cg] = v;
        } else {
          const int bb = rg >> 11, ss = rg & (SEQ - 1);
          const int hh = cg >> 6, dd = cg & (HD - 1);
          ((unsigned short*)Cout)[(((size_t)(bb * NH + hh) * SEQ + ss) * HD) + dd] = f2b(v);
        }
      }
    }
  }
}

// Flash attention, bf16 MFMA, fused local-diffusion blend.
// Q,K,V: [B*H][S][64] bf16.  Y: [B][S][1024] bf16 (head de-interleaved).
// Block: 128 q-rows, 4 waves x 32 rows; KV tile 64.
__global__ __launch_bounds__(256, 2)
void attn_mfma(const unsigned short* __restrict__ Q, const unsigned short* __restrict__ K,
               const unsigned short* __restrict__ V, unsigned short* __restrict__ Y) {
  __shared__ char Plds[128 * 128];  // P[128 rows][64 keys] bf16, XOR-swizzled rows
  __shared__ char Vt[64 * 128];     // V^T[64 d][64 keys] bf16, XOR-swizzled rows
  const int tid = threadIdx.x, lane = tid & 63, w = tid >> 6;
  const int p = lane & 15, g = lane >> 4;
  const int bh = blockIdx.y, b = bh >> 4, h = bh & 15;
  const int q0 = blockIdx.x * 128;
  const size_t base = (size_t)bh * SEQ * HD;
  const unsigned short* Qp = Q + base;
  const unsigned short* Kp = K + base;
  const unsigned short* Vp = V + base;
  const int qw = q0 + w * 32;

  // Q fragments in registers for the whole kernel (A-operand, k-map g*8+j)
  bf16x8 qf[2][2];
#pragma unroll
  for (int mi = 0; mi < 2; ++mi)
#pragma unroll
    for (int ks = 0; ks < 2; ++ks)
      qf[mi][ks] = *(const bf16x8*)&Qp[(size_t)(qw + mi * 16 + p) * HD + ks * 32 + g * 8];

  f32x4 o[2][4];
  float mr[8], lr[8];
#pragma unroll
  for (int mi = 0; mi < 2; ++mi)
#pragma unroll
    for (int nf = 0; nf < 4; ++nf)
      o[mi][nf] = (f32x4){0.f, 0.f, 0.f, 0.f};
#pragma unroll
  for (int i = 0; i < 8; ++i) { mr[i] = -INFINITY; lr[i] = 0.f; }

  const int vkey = tid & 63, vc2 = tid >> 6;

  for (int kb = 0; kb < SEQ; kb += 64) {
    // K fragments direct from global (B-operand of QK^T: col = key row of K)
    bf16x8 kf[4][2];
#pragma unroll
    for (int nf = 0; nf < 4; ++nf)
#pragma unroll
      for (int ks = 0; ks < 2; ++ks)
        kf[nf][ks] = *(const bf16x8*)&Kp[(size_t)(kb + nf * 16 + p) * HD + ks * 32 + g * 8];
    // V tile to registers (for transposed LDS staging)
    union { bf16x8 v; unsigned short u[8]; } vv[2];
    vv[0].v = *(const bf16x8*)&Vp[(size_t)(kb + vkey) * HD + vc2 * 8];
    vv[1].v = *(const bf16x8*)&Vp[(size_t)(kb + vkey) * HD + vc2 * 8 + 32];

    // S = Q K^T
    f32x4 s[2][4];
#pragma unroll
    for (int mi = 0; mi < 2; ++mi)
#pragma unroll
      for (int nf = 0; nf < 4; ++nf)
        s[mi][nf] = (f32x4){0.f, 0.f, 0.f, 0.f};
#pragma unroll
    for (int mi = 0; mi < 2; ++mi)
#pragma unroll
      for (int nf = 0; nf < 4; ++nf)
#pragma unroll
        for (int ks = 0; ks < 2; ++ks)
          s[mi][nf] = __builtin_amdgcn_mfma_f32_16x16x32_bf16(qf[mi][ks], kf[nf][ks], s[mi][nf], 0, 0, 0);

    // online softmax (row r lives in 16 lanes of one quarter-wave)
#pragma unroll
    for (int mi = 0; mi < 2; ++mi) {
#pragma unroll
      for (int j = 0; j < 4; ++j) {
        float tm = fmaxf(fmaxf(s[mi][0][j], s[mi][1][j]), fmaxf(s[mi][2][j], s[mi][3][j]));
        tm = fmaxf(tm, __shfl_xor(tm, 1));
        tm = fmaxf(tm, __shfl_xor(tm, 2));
        tm = fmaxf(tm, __shfl_xor(tm, 4));
        tm = fmaxf(tm, __shfl_xor(tm, 8));
        tm *= SCL;
        const int ridx = mi * 4 + j;
        const float om = mr[ridx];
        const float nm = fmaxf(om, tm);
        float rs = 0.f;
#pragma unroll
        for (int nf = 0; nf < 4; ++nf) {
          const float e = __expf(s[mi][nf][j] * SCL - nm);
          s[mi][nf][j] = e;
          rs += e;
        }
        rs += __shfl_xor(rs, 1);
        rs += __shfl_xor(rs, 2);
        rs += __shfl_xor(rs, 4);
        rs += __shfl_xor(rs, 8);
        const float rc = __expf(om - nm);
        mr[ridx] = nm;
        lr[ridx] = lr[ridx] * rc + rs;
#pragma unroll
        for (int nf = 0; nf < 4; ++nf) o[mi][nf][j] *= rc;
      }
    }

    __syncthreads();  // prev tile's PV reads of Plds/Vt complete
    // stage V^T (swizzle: byte ^= (row&7)<<4 within 128B row)
#pragma unroll
    for (int half = 0; half < 2; ++half) {
      const int d0 = vc2 * 8 + half * 32;
#pragma unroll
      for (int e = 0; e < 8; ++e) {
        const int d = d0 + e;
        *(unsigned short*)&Vt[d * 128 + ((2 * vkey) ^ ((d & 7) << 4))] = vv[half].u[e];
      }
    }
    // stage P (same swizzle)
#pragma unroll
    for (int mi = 0; mi < 2; ++mi)
#pragma unroll
      for (int j = 0; j < 4; ++j) {
        const int r = w * 32 + mi * 16 + g * 4 + j;
        const int swz = (r & 7) << 4;
#pragma unroll
        for (int nf = 0; nf < 4; ++nf) {
          const int c = nf * 16 + p;
          *(unsigned short*)&Plds[r * 128 + ((2 * c) ^ swz)] = f2b(s[mi][nf][j]);
        }
      }
    __syncthreads();

    // O += P @ V   (A=P rows, B=V^T rows as cols; same k-map both sides)
    bf16x8 paf[2][2], vbf[4][2];
#pragma unroll
    for (int mi = 0; mi < 2; ++mi) {
      const int r = w * 32 + mi * 16 + p;
      const int swz = (r & 7) << 4;
#pragma unroll
      for (int ks = 0; ks < 2; ++ks)
        paf[mi][ks] = *(const bf16x8*)&Plds[r * 128 + ((ks * 64 + g * 16) ^ swz)];
    }
#pragma unroll
    for (int nf = 0; nf < 4; ++nf) {
      const int d = nf * 16 + p;
      const int swz = (d & 7) << 4;
#pragma unroll
      for (int ks = 0; ks < 2; ++ks)
        vbf[nf][ks] = *(const bf16x8*)&Vt[d * 128 + ((ks * 64 + g * 16) ^ swz)];
    }
#pragma unroll
    for (int mi = 0; mi < 2; ++mi)
#pragma unroll
      for (int nf = 0; nf < 4; ++nf)
#pragma unroll
        for (int ks = 0; ks < 2; ++ks)
          o[mi][nf] = __builtin_amdgcn_mfma_f32_16x16x32_bf16(paf[mi][ks], vbf[nf][ks], o[mi][nf], 0, 0, 0);
  }

  // epilogue: 0.6*softmax@V + 0.4*(L@V), write bf16 [B,S,D]
  const float e1 = 4.3936934e-2f;   // exp(-3.125)
  const float e2 = 3.7266532e-6f;   // exp(-12.5)
  const float e3 = 6.1022e-13f;     // exp(-28.125)
  const float lwv[4] = {1.f, e1, e2, e3};
#pragma unroll
  for (int mi = 0; mi < 2; ++mi)
#pragma unroll
    for (int j = 0; j < 4; ++j) {
      const int q = qw + mi * 16 + g * 4 + j;
      const float inv = 0.6f / lr[mi * 4 + j];
      float wsum = 0.f;
#pragma unroll
      for (int dd = -3; dd <= 3; ++dd) {
        const int kk = q + dd;
        if (kk >= 0 && kk < SEQ) wsum += lwv[dd < 0 ? -dd : dd];
      }
      const float wn = 0.4f / (wsum + 1e-10f);
#pragma unroll
      for (int nf = 0; nf < 4; ++nf) {
        const int d = nf * 16 + p;
        float loc = 0.f;
#pragma unroll
        for (int dd = -3; dd <= 3; ++dd) {
          const int kk = q + dd;
          if (kk >= 0 && kk < SEQ) loc += lwv[dd < 0 ? -dd : dd] * b2f(Vp[(size_t)kk * HD + d]);
        }
        const float val = o[mi][nf][j] * inv + loc * wn;
        Y[((size_t)(b * SEQ) + q) * DIMC + h * HD + d] = f2b(val);
      }
    }
}

extern "C" void kernel_launch(void* const* d_in, const int* in_sizes, int n_in,
                              void* d_out, int out_size, void* d_ws, size_t ws_size,
                              hipStream_t stream) {
  (void)in_sizes; (void)n_in; (void)out_size; (void)ws_size;
  const float* x  = (const float*)d_in[0];
  const float* Wq = (const float*)d_in[1];
  const float* bq = (const float*)d_in[2];
  const float* Wk = (const float*)d_in[3];
  const float* bk = (const float*)d_in[4];
  const float* Wv = (const float*)d_in[5];
  const float* bv = (const float*)d_in[6];
  const float* Wo = (const float*)d_in[7];
  const float* bo = (const float*)d_in[8];

  char* ws = (char*)d_ws;
  unsigned short* xb  = (unsigned short*)(ws);               //  8 MB [4096][1024]
  unsigned short* Wqb = (unsigned short*)(ws + 8388608);     //  2 MB each
  unsigned short* Wkb = (unsigned short*)(ws + 10485760);
  unsigned short* Wvb = (unsigned short*)(ws + 12582912);
  unsigned short* Wob = (unsigned short*)(ws + 14680064);
  unsigned short* Qh  = (unsigned short*)(ws + 16777216);    //  8 MB [32][2048][64]
  unsigned short* Kh  = (unsigned short*)(ws + 25165824);
  unsigned short* Vh  = (unsigned short*)(ws + 33554432);
  unsigned short* Yb  = (unsigned short*)(ws + 41943040);    //  8 MB [4096][1024]

  dim3 blk(256);
  cvt_bf16<<<2048, blk, 0, stream>>>(x,  xb,  524288);
  cvt_bf16<<<512,  blk, 0, stream>>>(Wq, Wqb, 131072);
  cvt_bf16<<<512,  blk, 0, stream>>>(Wk, Wkb, 131072);
  cvt_bf16<<<512,  blk, 0, stream>>>(Wv, Wvb, 131072);
  cvt_bf16<<<512,  blk, 0, stream>>>(Wo, Wob, 131072);

  dim3 gg(32, 16);  // M/128 x N/64
  gemm_bf16<1><<<gg, blk, 0, stream>>>(xb, Wqb, bq, Qh);
  gemm_bf16<1><<<gg, blk, 0, stream>>>(xb, Wkb, bk, Kh);
  gemm_bf16<1><<<gg, blk, 0, stream>>>(xb, Wvb, bv, Vh);

  attn_mfma<<<dim3(16, 32), blk, 0, stream>>>(Qh, Kh, Vh, Yb);

  gemm_bf16<0><<<gg, blk, 0, stream>>>(Yb, Wob, bo, d_out);
}

// Round 4
// 186.908 us; speedup vs baseline: 5.8197x; 1.3662x over previous
//
#include <hip/hip_runtime.h>
#include <math.h>

typedef __bf16 bf16x8 __attribute__((ext_vector_type(8)));
typedef float f32x4 __attribute__((ext_vector_type(4)));

namespace {
constexpr int DIMC = 1024, NH = 16, HD = 64, SEQ = 2048;
constexpr float SCL = 0.125f;  // 1/(tau*sqrt(64))
}

__device__ __forceinline__ unsigned short f2b(float f) {
  unsigned u = __float_as_uint(f);
  return (unsigned short)((u + 0x7fffu + ((u >> 16) & 1u)) >> 16);
}
__device__ __forceinline__ float b2f(unsigned short s) {
  return __uint_as_float((unsigned)s << 16);
}
__device__ __forceinline__ unsigned cvtpk(float lo, float hi) {
  unsigned r;
  asm("v_cvt_pk_bf16_f32 %0, %1, %2" : "=v"(r) : "v"(lo), "v"(hi));
  return r;
}

// fp32 -> bf16 (RNE), 8 elements per thread
__global__ __launch_bounds__(256)
void cvt_bf16(const float* __restrict__ in, unsigned short* __restrict__ out, int n8) {
  int i = blockIdx.x * 256 + threadIdx.x;
  if (i >= n8) return;
  const float4* in4 = (const float4*)in;
  float4 a = in4[2 * i], b = in4[2 * i + 1];
  union { unsigned short u[8]; uint4 v; } r;
  r.u[0] = f2b(a.x); r.u[1] = f2b(a.y); r.u[2] = f2b(a.z); r.u[3] = f2b(a.w);
  r.u[4] = f2b(b.x); r.u[5] = f2b(b.y); r.u[6] = f2b(b.z); r.u[7] = f2b(b.w);
  ((uint4*)out)[i] = r.v;
}

// all 4 weight matrices in one launch; outputs contiguous
__global__ __launch_bounds__(256)
void cvt_w4(const float* __restrict__ w0, const float* __restrict__ w1,
            const float* __restrict__ w2, const float* __restrict__ w3,
            unsigned short* __restrict__ out) {
  const int which = blockIdx.y;
  const float* src = which == 0 ? w0 : which == 1 ? w1 : which == 2 ? w2 : w3;
  unsigned short* dst = out + (size_t)which * 1048576;
  int i = blockIdx.x * 256 + threadIdx.x;
  const float4* in4 = (const float4*)src;
  float4 a = in4[2 * i], b = in4[2 * i + 1];
  union { unsigned short u[8]; uint4 v; } r;
  r.u[0] = f2b(a.x); r.u[1] = f2b(a.y); r.u[2] = f2b(a.z); r.u[3] = f2b(a.w);
  r.u[4] = f2b(b.x); r.u[5] = f2b(b.y); r.u[6] = f2b(b.z); r.u[7] = f2b(b.w);
  ((uint4*)dst)[i] = r.v;
}

// C = A @ W^T + bias.  A:[4096,1024] bf16 rm, W:[1024,1024] bf16 rm.
// MODE 0: fp32 [M,N] out.  MODE 1: bf16 head-interleaved [B*H,S,hd] out.
// EXACT round-2 version (reg-staged, passed at 3.9e-3).
template<int MODE>
__global__ __launch_bounds__(256, 2)
void gemm_bf16(const unsigned short* __restrict__ A, const unsigned short* __restrict__ W,
               const float* __restrict__ bias, void* __restrict__ Cout) {
  __shared__ char As[8192];  // [128][32] bf16
  __shared__ char Bs[4096];  // [64][32] bf16
  const int tid = threadIdx.x, lane = tid & 63, w = tid >> 6;
  const int p = lane & 15, g = lane >> 4;
  const int wr = w >> 1, wc = w & 1;
  const int bm = blockIdx.x * 128, bn = blockIdx.y * 64;
  const int sr = tid >> 2, sc = (tid & 3) * 8;

  f32x4 acc[4][2];
#pragma unroll
  for (int mf = 0; mf < 4; ++mf)
#pragma unroll
    for (int nf = 0; nf < 2; ++nf)
      acc[mf][nf] = (f32x4){0.f, 0.f, 0.f, 0.f};

  const size_t arow0 = (size_t)(bm + sr) * DIMC + sc;
  const size_t arow1 = (size_t)(bm + 64 + sr) * DIMC + sc;
  const size_t brow  = (size_t)(bn + sr) * DIMC + sc;

  for (int k0 = 0; k0 < DIMC; k0 += 32) {
    const bf16x8 va0 = *(const bf16x8*)&A[arow0 + k0];
    const bf16x8 va1 = *(const bf16x8*)&A[arow1 + k0];
    const bf16x8 vb  = *(const bf16x8*)&W[brow + k0];
    __syncthreads();   // previous tile's reads complete
    *(bf16x8*)&As[tid * 16] = va0;
    *(bf16x8*)&As[4096 + tid * 16] = va1;
    *(bf16x8*)&Bs[tid * 16] = vb;
    __syncthreads();
    bf16x8 af[4], bfr[2];
#pragma unroll
    for (int mf = 0; mf < 4; ++mf)
      af[mf] = *(const bf16x8*)&As[(wr * 64 + mf * 16 + p) * 64 + g * 16];
#pragma unroll
    for (int nf = 0; nf < 2; ++nf)
      bfr[nf] = *(const bf16x8*)&Bs[(wc * 32 + nf * 16 + p) * 64 + g * 16];
#pragma unroll
    for (int mf = 0; mf < 4; ++mf)
#pragma unroll
      for (int nf = 0; nf < 2; ++nf)
        acc[mf][nf] = __builtin_amdgcn_mfma_f32_16x16x32_bf16(af[mf], bfr[nf], acc[mf][nf], 0, 0, 0);
  }

#pragma unroll
  for (int nf = 0; nf < 2; ++nf) {
    const int cg = bn + wc * 32 + nf * 16 + p;
    const float bv = bias[cg];
#pragma unroll
    for (int mf = 0; mf < 4; ++mf) {
#pragma unroll
      for (int j = 0; j < 4; ++j) {
        const int rg = bm + wr * 64 + mf * 16 + g * 4 + j;
        const float v = acc[mf][nf][j] + bv;
        if (MODE == 0) {
          ((float*)Cout)[(size_t)rg * DIMC + cg] = v;
        } else {
          const int bb = rg >> 11, ss = rg & (SEQ - 1);
          const int hh = cg >> 6, dd = cg & (HD - 1);
          ((unsigned short*)Cout)[(((size_t)(bb * NH + hh) * SEQ + ss) * HD) + dd] = f2b(v);
        }
      }
    }
  }
}

// Flash attention, swapped-operand MFMA (q lane-local softmax), P^T via LDS.
// Q,K,V: [B*H][S][64] bf16.  Y: [B][S][1024] bf16.
__global__ __launch_bounds__(256, 2)
void attn_mfma(const unsigned short* __restrict__ Q, const unsigned short* __restrict__ K,
               const unsigned short* __restrict__ V, unsigned short* __restrict__ Y) {
  __shared__ char Vt[2][8192];   // V^T [64 d][64 key] bf16, XOR-swizzled, dbuf
  __shared__ char Pl[2][16384];  // P [128 q][64 key] bf16, XOR-swizzled, dbuf
  const int tid = threadIdx.x, lane = tid & 63, w = tid >> 6;
  const int p = lane & 15, g = lane >> 4;
  const int bh = blockIdx.y, b = bh >> 4, h = bh & 15;
  const int q0 = blockIdx.x * 128, qw = q0 + w * 32;
  const size_t base = (size_t)bh * SEQ * HD;
  const unsigned short* Qp = Q + base;
  const unsigned short* Kp = K + base;
  const unsigned short* Vp = V + base;

  // Q fragments: B-operand (col=q). lane(p,g): q=qw+mi*16+p, k(d)=ks*32+g*8+j
  bf16x8 qf[2][2];
#pragma unroll
  for (int mi = 0; mi < 2; ++mi)
#pragma unroll
    for (int ks = 0; ks < 2; ++ks)
      qf[mi][ks] = *(const bf16x8*)&Qp[(size_t)(qw + mi * 16 + p) * HD + ks * 32 + g * 8];

  f32x4 o2[2][4];   // O^T frags: col q = mi*16+p, row d = nfd*16+g*4+j
#pragma unroll
  for (int mi = 0; mi < 2; ++mi)
#pragma unroll
    for (int nf = 0; nf < 4; ++nf)
      o2[mi][nf] = (f32x4){0.f, 0.f, 0.f, 0.f};
  float m2[2] = {-INFINITY, -INFINITY}, lr[2] = {0.f, 0.f};

  const int kp = tid & 31, vd0 = (tid >> 5) * 8;  // V-stage mapping

  for (int kb = 0; kb < SEQ; kb += 64) {
    const int par = (kb >> 6) & 1;
    // K fragments: A-operand (row=key). lane(p,g): key=kb+nf*16+p, k(d)=ks*32+g*8+j
    bf16x8 kf[4][2];
#pragma unroll
    for (int nf = 0; nf < 4; ++nf)
#pragma unroll
      for (int ks = 0; ks < 2; ++ks)
        kf[nf][ks] = *(const bf16x8*)&Kp[(size_t)(kb + nf * 16 + p) * HD + ks * 32 + g * 8];
    // V tile: key-pair x 8d per thread
    union { bf16x8 v; unsigned short u[8]; } v0, v1;
    v0.v = *(const bf16x8*)&Vp[(size_t)(kb + 2 * kp) * HD + vd0];
    v1.v = *(const bf16x8*)&Vp[(size_t)(kb + 2 * kp + 1) * HD + vd0];

    // S^T = K Q^T : frag(mi,nf), lane(p,g): S[q=qw+mi*16+p][key=kb+nf*16+g*4+j]
    f32x4 s2[2][4];
#pragma unroll
    for (int mi = 0; mi < 2; ++mi)
#pragma unroll
      for (int nf = 0; nf < 4; ++nf)
        s2[mi][nf] = (f32x4){0.f, 0.f, 0.f, 0.f};
#pragma unroll
    for (int mi = 0; mi < 2; ++mi)
#pragma unroll
      for (int nf = 0; nf < 4; ++nf)
#pragma unroll
        for (int ks = 0; ks < 2; ++ks)
          s2[mi][nf] = __builtin_amdgcn_mfma_f32_16x16x32_bf16(kf[nf][ks], qf[mi][ks], s2[mi][nf], 0, 0, 0);

    // lane-local online softmax (q = lane's column), pack P to bf16 pairs
    unsigned pk[2][8];
#pragma unroll
    for (int mi = 0; mi < 2; ++mi) {
      float tm = s2[mi][0][0];
#pragma unroll
      for (int nf = 0; nf < 4; ++nf)
#pragma unroll
        for (int j = 0; j < 4; ++j) tm = fmaxf(tm, s2[mi][nf][j]);
      tm = fmaxf(tm, __shfl_xor(tm, 16));
      tm = fmaxf(tm, __shfl_xor(tm, 32));
      tm *= SCL;
      const float nm = fmaxf(m2[mi], tm);
      float rs = 0.f;
#pragma unroll
      for (int nf = 0; nf < 4; ++nf)
#pragma unroll
        for (int j = 0; j < 4; ++j) {
          const float e = __expf(s2[mi][nf][j] * SCL - nm);
          s2[mi][nf][j] = e;
          rs += e;
        }
      rs += __shfl_xor(rs, 16);
      rs += __shfl_xor(rs, 32);
      const float rc = __expf(m2[mi] - nm);
      lr[mi] = lr[mi] * rc + rs;
      m2[mi] = nm;
#pragma unroll
      for (int nf = 0; nf < 4; ++nf)
#pragma unroll
        for (int j = 0; j < 4; ++j) o2[mi][nf][j] *= rc;
#pragma unroll
      for (int nf = 0; nf < 4; ++nf) {
        pk[mi][2 * nf]     = cvtpk(s2[mi][nf][0], s2[mi][nf][1]);
        pk[mi][2 * nf + 1] = cvtpk(s2[mi][nf][2], s2[mi][nf][3]);
      }
    }

    // stage P: row q = w*32+mi*16+p, cols keys nf*16+g*4+{2t,2t+1} as u32
#pragma unroll
    for (int mi = 0; mi < 2; ++mi) {
      const int r = w * 32 + mi * 16 + p;
      const int swz = (r & 7) << 4;
#pragma unroll
      for (int nf = 0; nf < 4; ++nf)
#pragma unroll
        for (int t = 0; t < 2; ++t)
          *(unsigned*)&Pl[par][r * 128 + ((nf * 32 + g * 8 + 4 * t) ^ swz)] = pk[mi][2 * nf + t];
    }
    // stage V^T (paired keys -> u32), swizzle byte ^= (d&7)<<4
#pragma unroll
    for (int e = 0; e < 8; ++e) {
      const int d = vd0 + e;
      const unsigned val = (unsigned)v0.u[e] | ((unsigned)v1.u[e] << 16);
      *(unsigned*)&Vt[par][d * 128 + ((kp * 4) ^ ((d & 7) << 4))] = val;
    }
    __syncthreads();

    // O^T += V^T · P^T  (A = V^T rows d; B = P rows q read as cols)
    bf16x8 pf[2][2], vb[4][2];
#pragma unroll
    for (int mi = 0; mi < 2; ++mi) {
      const int r = w * 32 + mi * 16 + p;
      const int swz = (r & 7) << 4;
#pragma unroll
      for (int ks = 0; ks < 2; ++ks)
        pf[mi][ks] = *(const bf16x8*)&Pl[par][r * 128 + ((ks * 64 + g * 16) ^ swz)];
    }
#pragma unroll
    for (int nfd = 0; nfd < 4; ++nfd) {
      const int d = nfd * 16 + p;
      const int swz = (d & 7) << 4;
#pragma unroll
      for (int ks = 0; ks < 2; ++ks)
        vb[nfd][ks] = *(const bf16x8*)&Vt[par][d * 128 + ((ks * 64 + g * 16) ^ swz)];
    }
#pragma unroll
    for (int mi = 0; mi < 2; ++mi)
#pragma unroll
      for (int nfd = 0; nfd < 4; ++nfd)
#pragma unroll
        for (int ks = 0; ks < 2; ++ks)
          o2[mi][nfd] = __builtin_amdgcn_mfma_f32_16x16x32_bf16(vb[nfd][ks], pf[mi][ks], o2[mi][nfd], 0, 0, 0);
  }

  // epilogue: out = 0.6*O/l + 0.4*(L@V); q lane-local, d contiguous by 4
  const float e1 = 4.3936934e-2f, e2 = 3.7266532e-6f, e3 = 6.1019804e-13f;
  const float lwv[4] = {1.f, e1, e2, e3};
#pragma unroll
  for (int mi = 0; mi < 2; ++mi) {
    const int q = qw + mi * 16 + p;
    const float inv = 0.6f / lr[mi];
    float wsum = 0.f;
#pragma unroll
    for (int dd = -3; dd <= 3; ++dd) {
      const int kk = q + dd;
      if (kk >= 0 && kk < SEQ) wsum += lwv[dd < 0 ? -dd : dd];
    }
    const float wn = 0.4f / (wsum + 1e-10f);
#pragma unroll
    for (int nfd = 0; nfd < 4; ++nfd) {
      const int d0 = nfd * 16 + g * 4;
      float loc[4] = {0.f, 0.f, 0.f, 0.f};
#pragma unroll
      for (int dd = -3; dd <= 3; ++dd) {
        const int kk = q + dd;
        if (kk >= 0 && kk < SEQ) {
          const uint2 lv = *(const uint2*)&Vp[(size_t)kk * HD + d0];
          const float wt = lwv[dd < 0 ? -dd : dd];
          loc[0] = fmaf(wt, b2f((unsigned short)lv.x), loc[0]);
          loc[1] = fmaf(wt, b2f((unsigned short)(lv.x >> 16)), loc[1]);
          loc[2] = fmaf(wt, b2f((unsigned short)lv.y), loc[2]);
          loc[3] = fmaf(wt, b2f((unsigned short)(lv.y >> 16)), loc[3]);
        }
      }
      uint2 st;
      st.x = cvtpk(o2[mi][nfd][0] * inv + loc[0] * wn, o2[mi][nfd][1] * inv + loc[1] * wn);
      st.y = cvtpk(o2[mi][nfd][2] * inv + loc[2] * wn, o2[mi][nfd][3] * inv + loc[3] * wn);
      *(uint2*)&Y[((size_t)(b * SEQ + q)) * DIMC + h * HD + d0] = st;
    }
  }
}

extern "C" void kernel_launch(void* const* d_in, const int* in_sizes, int n_in,
                              void* d_out, int out_size, void* d_ws, size_t ws_size,
                              hipStream_t stream) {
  (void)in_sizes; (void)n_in; (void)out_size; (void)ws_size;
  const float* x  = (const float*)d_in[0];
  const float* Wq = (const float*)d_in[1];
  const float* bq = (const float*)d_in[2];
  const float* Wk = (const float*)d_in[3];
  const float* bk = (const float*)d_in[4];
  const float* Wv = (const float*)d_in[5];
  const float* bv = (const float*)d_in[6];
  const float* Wo = (const float*)d_in[7];
  const float* bo = (const float*)d_in[8];

  char* ws = (char*)d_ws;
  unsigned short* xb  = (unsigned short*)(ws);               // 8 MB
  unsigned short* Wqb = (unsigned short*)(ws + 8388608);     // 2 MB each, contiguous
  unsigned short* Wkb = (unsigned short*)(ws + 10485760);
  unsigned short* Wvb = (unsigned short*)(ws + 12582912);
  unsigned short* Wob = (unsigned short*)(ws + 14680064);
  unsigned short* Qh  = (unsigned short*)(ws + 16777216);    // 8 MB each
  unsigned short* Kh  = (unsigned short*)(ws + 25165824);
  unsigned short* Vh  = (unsigned short*)(ws + 33554432);
  unsigned short* Yb  = (unsigned short*)(ws + 41943040);

  dim3 blk(256);
  cvt_bf16<<<2048, blk, 0, stream>>>(x, xb, 524288);
  cvt_w4<<<dim3(512, 4), blk, 0, stream>>>(Wq, Wk, Wv, Wo, Wqb);

  dim3 gg(32, 16);  // M/128 x N/64
  gemm_bf16<1><<<gg, blk, 0, stream>>>(xb, Wqb, bq, Qh);
  gemm_bf16<1><<<gg, blk, 0, stream>>>(xb, Wkb, bk, Kh);
  gemm_bf16<1><<<gg, blk, 0, stream>>>(xb, Wvb, bv, Vh);

  attn_mfma<<<dim3(16, 32), blk, 0, stream>>>(Qh, Kh, Vh, Yb);

  gemm_bf16<0><<<gg, blk, 0, stream>>>(Yb, Wob, bo, (float*)d_out);
}

// Round 5
// 165.373 us; speedup vs baseline: 6.5776x; 1.1302x over previous
//
#include <hip/hip_runtime.h>
#include <math.h>

typedef __bf16 bf16x8 __attribute__((ext_vector_type(8)));
typedef float f32x4 __attribute__((ext_vector_type(4)));

namespace {
constexpr int DIMC = 1024, NH = 16, HD = 64, SEQ = 2048;
constexpr float SCL = 0.125f;  // 1/(tau*sqrt(64))
}

__device__ __forceinline__ unsigned short f2b(float f) {
  unsigned u = __float_as_uint(f);
  return (unsigned short)((u + 0x7fffu + ((u >> 16) & 1u)) >> 16);
}
__device__ __forceinline__ float b2f(unsigned short s) {
  return __uint_as_float((unsigned)s << 16);
}
__device__ __forceinline__ unsigned cvtpk(float lo, float hi) {
  unsigned r;
  asm("v_cvt_pk_bf16_f32 %0, %1, %2" : "=v"(r) : "v"(lo), "v"(hi));
  return r;
}

// fp32 -> bf16 (RNE), 8 elements per thread
__global__ __launch_bounds__(256)
void cvt_bf16(const float* __restrict__ in, unsigned short* __restrict__ out, int n8) {
  int i = blockIdx.x * 256 + threadIdx.x;
  if (i >= n8) return;
  const float4* in4 = (const float4*)in;
  float4 a = in4[2 * i], b = in4[2 * i + 1];
  union { unsigned short u[8]; uint4 v; } r;
  r.u[0] = f2b(a.x); r.u[1] = f2b(a.y); r.u[2] = f2b(a.z); r.u[3] = f2b(a.w);
  r.u[4] = f2b(b.x); r.u[5] = f2b(b.y); r.u[6] = f2b(b.z); r.u[7] = f2b(b.w);
  ((uint4*)out)[i] = r.v;
}

// all 4 weight matrices in one launch; outputs contiguous
__global__ __launch_bounds__(256)
void cvt_w4(const float* __restrict__ w0, const float* __restrict__ w1,
            const float* __restrict__ w2, const float* __restrict__ w3,
            unsigned short* __restrict__ out) {
  const int which = blockIdx.y;
  const float* src = which == 0 ? w0 : which == 1 ? w1 : which == 2 ? w2 : w3;
  unsigned short* dst = out + (size_t)which * 1048576;
  int i = blockIdx.x * 256 + threadIdx.x;
  const float4* in4 = (const float4*)src;
  float4 a = in4[2 * i], b = in4[2 * i + 1];
  union { unsigned short u[8]; uint4 v; } r;
  r.u[0] = f2b(a.x); r.u[1] = f2b(a.y); r.u[2] = f2b(a.z); r.u[3] = f2b(a.w);
  r.u[4] = f2b(b.x); r.u[5] = f2b(b.y); r.u[6] = f2b(b.z); r.u[7] = f2b(b.w);
  ((uint4*)dst)[i] = r.v;
}

// ---- shared GEMM tile body (round-2 proven, reg-staged) ----
// C = A @ W^T + bias for one 128x64 tile.  MODE 0: fp32 [M,N]. MODE 1: bf16 head-interleaved.
template<int MODE>
__device__ __forceinline__
void gemm_tile(const unsigned short* __restrict__ A, const unsigned short* __restrict__ W,
               const float* __restrict__ bias, void* __restrict__ Cout,
               int bm, int bn, char* As, char* Bs) {
  const int tid = threadIdx.x, lane = tid & 63, w = tid >> 6;
  const int p = lane & 15, g = lane >> 4;
  const int wr = w >> 1, wc = w & 1;
  const int sr = tid >> 2, sc = (tid & 3) * 8;

  f32x4 acc[4][2];
#pragma unroll
  for (int mf = 0; mf < 4; ++mf)
#pragma unroll
    for (int nf = 0; nf < 2; ++nf)
      acc[mf][nf] = (f32x4){0.f, 0.f, 0.f, 0.f};

  const size_t arow0 = (size_t)(bm + sr) * DIMC + sc;
  const size_t arow1 = (size_t)(bm + 64 + sr) * DIMC + sc;
  const size_t brow  = (size_t)(bn + sr) * DIMC + sc;

  for (int k0 = 0; k0 < DIMC; k0 += 32) {
    const bf16x8 va0 = *(const bf16x8*)&A[arow0 + k0];
    const bf16x8 va1 = *(const bf16x8*)&A[arow1 + k0];
    const bf16x8 vb  = *(const bf16x8*)&W[brow + k0];
    __syncthreads();   // previous tile's reads complete
    *(bf16x8*)&As[tid * 16] = va0;
    *(bf16x8*)&As[4096 + tid * 16] = va1;
    *(bf16x8*)&Bs[tid * 16] = vb;
    __syncthreads();
    bf16x8 af[4], bfr[2];
#pragma unroll
    for (int mf = 0; mf < 4; ++mf)
      af[mf] = *(const bf16x8*)&As[(wr * 64 + mf * 16 + p) * 64 + g * 16];
#pragma unroll
    for (int nf = 0; nf < 2; ++nf)
      bfr[nf] = *(const bf16x8*)&Bs[(wc * 32 + nf * 16 + p) * 64 + g * 16];
#pragma unroll
    for (int mf = 0; mf < 4; ++mf)
#pragma unroll
      for (int nf = 0; nf < 2; ++nf)
        acc[mf][nf] = __builtin_amdgcn_mfma_f32_16x16x32_bf16(af[mf], bfr[nf], acc[mf][nf], 0, 0, 0);
  }

#pragma unroll
  for (int nf = 0; nf < 2; ++nf) {
    const int cg = bn + wc * 32 + nf * 16 + p;
    const float bv = bias[cg & (DIMC - 1)];
#pragma unroll
    for (int mf = 0; mf < 4; ++mf) {
#pragma unroll
      for (int j = 0; j < 4; ++j) {
        const int rg = bm + wr * 64 + mf * 16 + g * 4 + j;
        const float v = acc[mf][nf][j] + bv;
        if (MODE == 0) {
          ((float*)Cout)[(size_t)rg * DIMC + cg] = v;
        } else {
          const int bb = rg >> 11, ss = rg & (SEQ - 1);
          const int hh = cg >> 6, dd = cg & (HD - 1);
          ((unsigned short*)Cout)[(((size_t)(bb * NH + hh) * SEQ + ss) * HD) + dd] = f2b(v);
        }
      }
    }
  }
}

__global__ __launch_bounds__(256, 2)
void gemm_out(const unsigned short* __restrict__ A, const unsigned short* __restrict__ W,
              const float* __restrict__ bias, float* __restrict__ Cout) {
  __shared__ char As[8192];
  __shared__ char Bs[4096];
  gemm_tile<0>(A, W, bias, Cout, blockIdx.x * 128, blockIdx.y * 64, As, Bs);
}

// fused Q/K/V projection: blockIdx.y in [0,48), which = y>>4 selects weight/bias/out
__global__ __launch_bounds__(256, 2)
void gemm_qkv(const unsigned short* __restrict__ A, const unsigned short* __restrict__ Wall,
              const float* __restrict__ bq, const float* __restrict__ bk,
              const float* __restrict__ bv, unsigned short* __restrict__ Out) {
  __shared__ char As[8192];
  __shared__ char Bs[4096];
  const int which = blockIdx.y >> 4;
  const unsigned short* W = Wall + (size_t)which * 1048576;
  const float* bias = which == 0 ? bq : which == 1 ? bk : bv;
  unsigned short* Cout = Out + (size_t)which * 4194304;
  gemm_tile<1>(A, W, bias, Cout, blockIdx.x * 128, (blockIdx.y & 15) * 64, As, Bs);
}

// Flash attention, swapped-operand MFMA (q lane-local softmax), P^T via LDS.
// grid: x = bh (32) -> XCD = bh%8 (head-local L2), y = q-tile (16).
// Reg-double-buffered K/V prefetch; T13 defer-max; T5 setprio.
__global__ __launch_bounds__(256, 2)
void attn_mfma(const unsigned short* __restrict__ Q, const unsigned short* __restrict__ K,
               const unsigned short* __restrict__ V, unsigned short* __restrict__ Y) {
  __shared__ char Vt[2][8192];   // V^T [64 d][64 key] bf16, XOR-swizzled, dbuf
  __shared__ char Pl[2][16384];  // P [128 q][64 key] bf16, XOR-swizzled, dbuf
  const int tid = threadIdx.x, lane = tid & 63, w = tid >> 6;
  const int p = lane & 15, g = lane >> 4;
  const int bh = blockIdx.x, b = bh >> 4, h = bh & 15;
  const int q0 = blockIdx.y * 128, qw = q0 + w * 32;
  const size_t base = (size_t)bh * SEQ * HD;
  const unsigned short* Qp = Q + base;
  const unsigned short* Kp = K + base;
  const unsigned short* Vp = V + base;

  union Vu { bf16x8 v; unsigned short u[8]; };

  // Q fragments: B-operand (col=q). lane(p,g): q=qw+mi*16+p, k(d)=ks*32+g*8+j
  bf16x8 qf[2][2];
#pragma unroll
  for (int mi = 0; mi < 2; ++mi)
#pragma unroll
    for (int ks = 0; ks < 2; ++ks)
      qf[mi][ks] = *(const bf16x8*)&Qp[(size_t)(qw + mi * 16 + p) * HD + ks * 32 + g * 8];

  f32x4 o2[2][4];   // O^T frags: col q = mi*16+p, row d = nfd*16+g*4+j
#pragma unroll
  for (int mi = 0; mi < 2; ++mi)
#pragma unroll
    for (int nf = 0; nf < 4; ++nf)
      o2[mi][nf] = (f32x4){0.f, 0.f, 0.f, 0.f};
  float m2[2] = {-INFINITY, -INFINITY}, lr[2] = {0.f, 0.f};

  const int kp = tid & 31, vd0 = (tid >> 5) * 8;  // V-stage mapping

  auto loadK = [&](bf16x8 (&KF)[4][2], int kb) {
#pragma unroll
    for (int nf = 0; nf < 4; ++nf)
#pragma unroll
      for (int ks = 0; ks < 2; ++ks)
        KF[nf][ks] = *(const bf16x8*)&Kp[(size_t)(kb + nf * 16 + p) * HD + ks * 32 + g * 8];
  };
  auto loadV = [&](Vu& V0, Vu& V1, int kb) {
    V0.v = *(const bf16x8*)&Vp[(size_t)(kb + 2 * kp) * HD + vd0];
    V1.v = *(const bf16x8*)&Vp[(size_t)(kb + 2 * kp + 1) * HD + vd0];
  };

  auto tile = [&](bf16x8 (&KF)[4][2], Vu& V0, Vu& V1,
                  bf16x8 (&KFN)[4][2], Vu& V0N, Vu& V1N, int kt) {
    const int par = kt & 1;
    const int kn = kt * 64 + 64;
    if (kn < SEQ) { loadK(KFN, kn); loadV(V0N, V1N, kn); }  // prefetch next tile

    // S^T = K Q^T : frag(mi,nf), lane(p,g): S[q=qw+mi*16+p][key=kt*64+nf*16+g*4+j]
    f32x4 s2[2][4];
#pragma unroll
    for (int mi = 0; mi < 2; ++mi)
#pragma unroll
      for (int nf = 0; nf < 4; ++nf)
        s2[mi][nf] = (f32x4){0.f, 0.f, 0.f, 0.f};
    __builtin_amdgcn_s_setprio(1);
#pragma unroll
    for (int mi = 0; mi < 2; ++mi)
#pragma unroll
      for (int nf = 0; nf < 4; ++nf)
#pragma unroll
        for (int ks = 0; ks < 2; ++ks)
          s2[mi][nf] = __builtin_amdgcn_mfma_f32_16x16x32_bf16(KF[nf][ks], qf[mi][ks], s2[mi][nf], 0, 0, 0);
    __builtin_amdgcn_s_setprio(0);

    // lane-local online softmax (q = lane's column) with defer-max (THR=8)
    unsigned pk[2][8];
#pragma unroll
    for (int mi = 0; mi < 2; ++mi) {
      float tm = s2[mi][0][0];
#pragma unroll
      for (int nf = 0; nf < 4; ++nf)
#pragma unroll
        for (int j = 0; j < 4; ++j) tm = fmaxf(tm, s2[mi][nf][j]);
      tm = fmaxf(tm, __shfl_xor(tm, 16));
      tm = fmaxf(tm, __shfl_xor(tm, 32));
      tm *= SCL;
      float nm;
      if (__all(tm - m2[mi] <= 8.0f)) {
        nm = m2[mi];                       // defer: keep old max, no rescale
      } else {
        nm = fmaxf(m2[mi], tm);
        const float rc = __expf(m2[mi] - nm);
        lr[mi] *= rc;
#pragma unroll
        for (int nf = 0; nf < 4; ++nf)
#pragma unroll
          for (int j = 0; j < 4; ++j) o2[mi][nf][j] *= rc;
        m2[mi] = nm;
      }
      float rs = 0.f;
#pragma unroll
      for (int nf = 0; nf < 4; ++nf)
#pragma unroll
        for (int j = 0; j < 4; ++j) {
          const float e = __expf(s2[mi][nf][j] * SCL - nm);
          s2[mi][nf][j] = e;
          rs += e;
        }
      rs += __shfl_xor(rs, 16);
      rs += __shfl_xor(rs, 32);
      lr[mi] += rs;
#pragma unroll
      for (int nf = 0; nf < 4; ++nf) {
        pk[mi][2 * nf]     = cvtpk(s2[mi][nf][0], s2[mi][nf][1]);
        pk[mi][2 * nf + 1] = cvtpk(s2[mi][nf][2], s2[mi][nf][3]);
      }
    }

    // stage P: row q = w*32+mi*16+p, cols keys nf*16+g*4+{2t,2t+1} as u32
#pragma unroll
    for (int mi = 0; mi < 2; ++mi) {
      const int r = w * 32 + mi * 16 + p;
      const int swz = (r & 7) << 4;
#pragma unroll
      for (int nf = 0; nf < 4; ++nf)
#pragma unroll
        for (int t = 0; t < 2; ++t)
          *(unsigned*)&Pl[par][r * 128 + ((nf * 32 + g * 8 + 4 * t) ^ swz)] = pk[mi][2 * nf + t];
    }
    // stage V^T (paired keys -> u32), swizzle byte ^= (d&7)<<4
#pragma unroll
    for (int e = 0; e < 8; ++e) {
      const int d = vd0 + e;
      const unsigned val = (unsigned)V0.u[e] | ((unsigned)V1.u[e] << 16);
      *(unsigned*)&Vt[par][d * 128 + ((kp * 4) ^ ((d & 7) << 4))] = val;
    }
    __syncthreads();

    // O^T += V^T · P^T  (A = V^T rows d; B = P rows q read as cols)
    bf16x8 pf[2][2], vb[4][2];
#pragma unroll
    for (int mi = 0; mi < 2; ++mi) {
      const int r = w * 32 + mi * 16 + p;
      const int swz = (r & 7) << 4;
#pragma unroll
      for (int ks = 0; ks < 2; ++ks)
        pf[mi][ks] = *(const bf16x8*)&Pl[par][r * 128 + ((ks * 64 + g * 16) ^ swz)];
    }
#pragma unroll
    for (int nfd = 0; nfd < 4; ++nfd) {
      const int d = nfd * 16 + p;
      const int swz = (d & 7) << 4;
#pragma unroll
      for (int ks = 0; ks < 2; ++ks)
        vb[nfd][ks] = *(const bf16x8*)&Vt[par][d * 128 + ((ks * 64 + g * 16) ^ swz)];
    }
    __builtin_amdgcn_s_setprio(1);
#pragma unroll
    for (int mi = 0; mi < 2; ++mi)
#pragma unroll
      for (int nfd = 0; nfd < 4; ++nfd)
#pragma unroll
        for (int ks = 0; ks < 2; ++ks)
          o2[mi][nfd] = __builtin_amdgcn_mfma_f32_16x16x32_bf16(vb[nfd][ks], pf[mi][ks], o2[mi][nfd], 0, 0, 0);
    __builtin_amdgcn_s_setprio(0);
  };

  // prologue + ping-pong main loop (static register double-buffer)
  bf16x8 kfA[4][2], kfB[4][2];
  Vu v0A, v1A, v0B, v1B;
  loadK(kfA, 0);
  loadV(v0A, v1A, 0);
  for (int kt = 0; kt < SEQ / 64; kt += 2) {
    tile(kfA, v0A, v1A, kfB, v0B, v1B, kt);
    tile(kfB, v0B, v1B, kfA, v0A, v1A, kt + 1);
  }

  // epilogue: out = 0.6*O/l + 0.4*(L@V); q lane-local, d contiguous by 4
  const float e1 = 4.3936934e-2f, e2 = 3.7266532e-6f, e3 = 6.1019804e-13f;
  const float lwv[4] = {1.f, e1, e2, e3};
#pragma unroll
  for (int mi = 0; mi < 2; ++mi) {
    const int q = qw + mi * 16 + p;
    const float inv = 0.6f / lr[mi];
    float wsum = 0.f;
#pragma unroll
    for (int dd = -3; dd <= 3; ++dd) {
      const int kk = q + dd;
      if (kk >= 0 && kk < SEQ) wsum += lwv[dd < 0 ? -dd : dd];
    }
    const float wn = 0.4f / (wsum + 1e-10f);
#pragma unroll
    for (int nfd = 0; nfd < 4; ++nfd) {
      const int d0 = nfd * 16 + g * 4;
      float loc[4] = {0.f, 0.f, 0.f, 0.f};
#pragma unroll
      for (int dd = -3; dd <= 3; ++dd) {
        const int kk = q + dd;
        if (kk >= 0 && kk < SEQ) {
          const uint2 lv = *(const uint2*)&Vp[(size_t)kk * HD + d0];
          const float wt = lwv[dd < 0 ? -dd : dd];
          loc[0] = fmaf(wt, b2f((unsigned short)lv.x), loc[0]);
          loc[1] = fmaf(wt, b2f((unsigned short)(lv.x >> 16)), loc[1]);
          loc[2] = fmaf(wt, b2f((unsigned short)lv.y), loc[2]);
          loc[3] = fmaf(wt, b2f((unsigned short)(lv.y >> 16)), loc[3]);
        }
      }
      uint2 st;
      st.x = cvtpk(o2[mi][nfd][0] * inv + loc[0] * wn, o2[mi][nfd][1] * inv + loc[1] * wn);
      st.y = cvtpk(o2[mi][nfd][2] * inv + loc[2] * wn, o2[mi][nfd][3] * inv + loc[3] * wn);
      *(uint2*)&Y[((size_t)(b * SEQ + q)) * DIMC + h * HD + d0] = st;
    }
  }
}

extern "C" void kernel_launch(void* const* d_in, const int* in_sizes, int n_in,
                              void* d_out, int out_size, void* d_ws, size_t ws_size,
                              hipStream_t stream) {
  (void)in_sizes; (void)n_in; (void)out_size; (void)ws_size;
  const float* x  = (const float*)d_in[0];
  const float* Wq = (const float*)d_in[1];
  const float* bq = (const float*)d_in[2];
  const float* Wk = (const float*)d_in[3];
  const float* bk = (const float*)d_in[4];
  const float* Wv = (const float*)d_in[5];
  const float* bv = (const float*)d_in[6];
  const float* Wo = (const float*)d_in[7];
  const float* bo = (const float*)d_in[8];

  char* ws = (char*)d_ws;
  unsigned short* xb  = (unsigned short*)(ws);               // 8 MB
  unsigned short* Wqb = (unsigned short*)(ws + 8388608);     // 2 MB each, contiguous (Wq,Wk,Wv,Wo)
  unsigned short* Wob = (unsigned short*)(ws + 14680064);
  unsigned short* Qh  = (unsigned short*)(ws + 16777216);    // 8 MB each, contiguous (Q,K,V)
  unsigned short* Kh  = (unsigned short*)(ws + 25165824);
  unsigned short* Vh  = (unsigned short*)(ws + 33554432);
  unsigned short* Yb  = (unsigned short*)(ws + 41943040);

  dim3 blk(256);
  cvt_bf16<<<2048, blk, 0, stream>>>(x, xb, 524288);
  cvt_w4<<<dim3(512, 4), blk, 0, stream>>>(Wq, Wk, Wv, Wo, Wqb);

  gemm_qkv<<<dim3(32, 48), blk, 0, stream>>>(xb, Wqb, bq, bk, bv, Qh);

  attn_mfma<<<dim3(32, 16), blk, 0, stream>>>(Qh, Kh, Vh, Yb);

  gemm_out<<<dim3(32, 16), blk, 0, stream>>>(Yb, Wob, bo, (float*)d_out);
}